// Round 5
// baseline (10.497 us; speedup 1.0000x reference)
//
#include <hip/hip_runtime.h>
#include <math.h>

// out[b, o, l] = sum_k x[b, o%16, l+k-511] * wav[o%16, k], B=8, C=S=16, L=1024.
// 256 output channels = 16 distinct rows, each broadcast 16x.
//
// wav[k] = poly(u)*exp(-u/2), u=(k/sigma)^2 decays below any tolerance for
// k > ~10*|sigma| (sigma = f_mod[i]*scale/(2*pi), a few units) -> effective
// kmax ~65-80 taps (runtime-derived, deterministic). Kernel is store-bound:
// 8.39 MB output + ~8.4 us fixed harness replay floor.
//
// Round 5: vectorized conv (2x ds_read_b64 + 1x uniform b128 per 4 taps),
// wave-uniform zero-output early-out for the left-pad region (3/4 waves of
// every half=0 block store zeros BEFORE the barrier and skip the loop).

__global__ __launch_bounds__(256)
void wavconv_kernel(const float* __restrict__ x,
                    const float* __restrict__ scales,
                    const float* __restrict__ f_mod,
                    const float* __restrict__ poly_mod,
                    const int*   __restrict__ i_ptr,
                    float* __restrict__ out)
{
    __shared__ float xs[1552];   // zero-padded x segment for this half
    __shared__ float wv[1032];   // wavelet taps, zero-padded to 4-tap boundary

    const int tid  = threadIdx.x;
    const int blk  = blockIdx.x;
    const int half = blk & 1;
    const int bc   = blk >> 1;     // b*16 + c
    const int c    = bc & 15;
    const int b    = bc >> 4;

    // ---- scalar params + runtime tap cutoff ----
    const int   ii = i_ptr[0];
    const float fm = f_mod[ii];
    const float p0 = poly_mod[ii * 3 + 0];
    const float p1 = poly_mod[ii * 3 + 1];
    const float p2 = poly_mod[ii * 3 + 2];
    const float sigma = fm * scales[c] * 0.15915494309189535f;  // fm*scale/(2*pi)
    int kmax = (int)(fabsf(sigma) * 10.0f) + 2;   // u > ~100 beyond -> negligible
    if (kmax > 1019) kmax = 1019;                 // window reads stay inside xs

    // ---- stage zero-padded x segment (global loads issue first) ----
    // xs[i] = x[bc][half*512 + i - 511], zero outside [0,1024)
    const int nstage = kmax + 520;
    const float* __restrict__ xrow = x + ((size_t)bc << 10);
    for (int i = tid; i < nstage; i += 256) {
        const int m = (half << 9) + i - 511;
        xs[i] = (m >= 0 && m < 1024) ? xrow[m] : 0.0f;
    }

    // ---- wavelet taps k in [0,kmax), zeros to the 4-tap boundary ----
    const float rs = 1.0f / sigma;
    for (int k = tid; k < kmax + 4; k += 256) {
        const float q  = (float)k * rs;
        const float u  = q * q;
        const float u2 = u * u;
        const float poly = 1.0f - p0 * u + p1 * u2 + p2 * u2 * u;
        const float val  = poly * __expf(-0.5f * u);
        wv[k] = (k < kmax) ? val : 0.0f;
    }

    // ---- outputs: thread owns (lo, lo+1) of this half ----
    const int lo  = tid << 1;            // 0..510
    const int wlo = (tid >> 6) << 7;     // lane0's lo for this wave
    // taps k < 384 - wlo only touch the left zero pad for every lane of this
    // wave (half=0): max m = (wlo+127) + k - 511 < 0. Wave-uniform.
    int kst = 0;
    if (half == 0) { kst = 384 - wlo; if (kst < 0) kst = 0; }
    const bool zwave = (half == 0) && (384 - wlo >= kmax);  // whole wave all-zero

    float* op = out + ((size_t)b << 18) + ((size_t)c << 10) + (half << 9) + lo;

    if (zwave) {   // store zeros before the barrier, overlap drain with conv
        const float2 z = make_float2(0.0f, 0.0f);
        float* p = op;
        #pragma unroll
        for (int rep = 0; rep < 16; ++rep) { *(float2*)p = z; p += 1 << 14; }
    }

    __syncthreads();

    if (!zwave) {
        float a0 = 0.0f, a1 = 0.0f;
        float2 A = *(const float2*)&xs[lo + kst];
        float2 B = *(const float2*)&xs[lo + kst + 2];
        #pragma unroll 4
        for (int k = kst; k < kmax; k += 4) {
            const float4 w4 = *(const float4*)&wv[k];        // uniform broadcast
            const float2 C  = *(const float2*)&xs[lo + k + 4];
            const float2 D  = *(const float2*)&xs[lo + k + 6];
            a0 = fmaf(A.x, w4.x, a0); a0 = fmaf(A.y, w4.y, a0);
            a0 = fmaf(B.x, w4.z, a0); a0 = fmaf(B.y, w4.w, a0);
            a1 = fmaf(A.y, w4.x, a1); a1 = fmaf(B.x, w4.y, a1);
            a1 = fmaf(B.y, w4.z, a1); a1 = fmaf(C.x, w4.w, a1);
            A = C; B = D;
        }
        const float2 res = make_float2(a0, a1);
        float* p = op;
        #pragma unroll
        for (int rep = 0; rep < 16; ++rep) { *(float2*)p = res; p += 1 << 14; }
    }
}

extern "C" void kernel_launch(void* const* d_in, const int* in_sizes, int n_in,
                              void* d_out, int out_size, void* d_ws, size_t ws_size,
                              hipStream_t stream)
{
    const float* x        = (const float*)d_in[0];
    const float* scales   = (const float*)d_in[1];
    const float* f_mod    = (const float*)d_in[2];
    const float* poly_mod = (const float*)d_in[3];
    const int*   i_ptr    = (const int*)d_in[4];
    float* out = (float*)d_out;

    wavconv_kernel<<<256, 256, 0, stream>>>(x, scales, f_mod, poly_mod, i_ptr, out);
}